// Round 3
// baseline (1274.005 us; speedup 1.0000x reference)
//
#include <hip/hip_runtime.h>
#include <hip/hip_bf16.h>

typedef __hip_bfloat16 bf16;
typedef __attribute__((ext_vector_type(8))) short short8;
typedef __attribute__((ext_vector_type(4))) float f32x4;

#define MAXN 0.996f      // (1 - 4e-3)/sqrt(c), c=1
#define MINN 1e-15f

__device__ __forceinline__ float b2f(short s) {
    union { unsigned u; float f; } c; c.u = ((unsigned)(unsigned short)s) << 16; return c.f;
}
__device__ __forceinline__ short f2b(float f) {   // RNE bf16
    union { float f; unsigned u; } c; c.f = f;
    unsigned r = c.u + 0x7FFF + ((c.u >> 16) & 1);
    return (short)(r >> 16);
}
__device__ __forceinline__ float cv(short v) { return b2f(v); }
__device__ __forceinline__ float cv(float v) { return v; }
__device__ __forceinline__ short tb(short v) { return v; }
__device__ __forceinline__ short tb(float v) { return f2b(v); }
__device__ __forceinline__ short8 ld8(const short* p) { return *(const short8*)p; }
__device__ __forceinline__ short8 ld8(const float* p) {
    float4 a = *(const float4*)p, b = *(const float4*)(p + 4);
    short8 r;
    r[0] = f2b(a.x); r[1] = f2b(a.y); r[2] = f2b(a.z); r[3] = f2b(a.w);
    r[4] = f2b(b.x); r[5] = f2b(b.y); r[6] = f2b(b.z); r[7] = f2b(b.w);
    return r;
}
__device__ __forceinline__ void ldf8(const short* p, float* f) {
    short8 v = *(const short8*)p;
#pragma unroll
    for (int j = 0; j < 8; ++j) f[j] = b2f(v[j]);
}
__device__ __forceinline__ void ldf8(const float* p, float* f) {
    float4 a = *(const float4*)p, b = *(const float4*)(p + 4);
    f[0] = a.x; f[1] = a.y; f[2] = a.z; f[3] = a.w;
    f[4] = b.x; f[5] = b.y; f[6] = b.z; f[7] = b.w;
}
__device__ __forceinline__ void st(short* p, float v) { *p = f2b(v); }
__device__ __forceinline__ void st(float* p, float v) { *p = v; }

__device__ __forceinline__ float wave_sum(float v) {
#pragma unroll
    for (int m = 1; m < 64; m <<= 1) v += __shfl_xor(v, m);
    return v;
}
__device__ __forceinline__ float red16(float v) {
#pragma unroll
    for (int m = 1; m < 16; m <<= 1) v += __shfl_xor(v, m);
    return v;
}
__device__ __forceinline__ float artanh_(float x) {
    x = fminf(fmaxf(x, -1.f + 1e-7f), 1.f - 1e-7f);
    return 0.5f * (log1pf(x) - log1pf(-x));
}
__device__ __forceinline__ float sigmoidf_(float x) { return 1.f / (1.f + expf(-x)); }

// flag: 0 = storage is bf16, 1 = storage is f32
template <typename T> __device__ __forceinline__ bool skip(const int* flag) {
    return *flag != (int)(sizeof(T) == 4);
}

// ---------------- dtype detector ----------------
__global__ void k_detect(const void* hid, int* flag) {
    const short* p = (const short*)hid;
    int t = threadIdx.x;
    int bad = 0;
    for (int i = t; i < 4096; i += 256) {
        unsigned u = (unsigned)(unsigned short)p[i];
        unsigned ex = (u >> 7) & 0xFF;
        if (ex >= 128) bad = 1;   // |v| >= 2 or NaN/Inf -> cannot be in-ball bf16 data
    }
    __shared__ int s;
    if (t == 0) s = 0;
    __syncthreads();
    if (bad) atomicOr(&s, 1);
    __syncthreads();
    if (t == 0) *flag = s;
}

// ---------------- prep ----------------
template <typename T>
__global__ void k_prep(const T* __restrict__ b1, const T* __restrict__ b2,
                       const T* __restrict__ bl, const T* __restrict__ bih,
                       const T* __restrict__ bhh, const T* __restrict__ Q,
                       const T* __restrict__ ratt, const T* __restrict__ Wih,
                       const T* __restrict__ Whh,
                       float* hb1, float* y2a, float* hb2, float* y2b,
                       float* blf, float* bs256, float* ratf,
                       short* QT, short* Wc, const int* flag) {
    if (skip<T>(flag)) return;
    __shared__ float sb[256];
    int t = threadIdx.x;
    float v1 = (t < 128) ? cv(b1[t]) : 0.f;
    sb[t] = v1 * v1; __syncthreads();
    for (int d = 128; d > 0; d >>= 1) { if (t < d) sb[t] += sb[t + d]; __syncthreads(); }
    float n2a = sb[0]; __syncthreads();
    {
        float un = fmaxf(sqrtf(n2a), MINN);
        float e = tanhf(un), tt = e / un;
        float s = (e > MAXN) ? MAXN / e : 1.f;
        if (t < 128) hb1[t] = s * tt * v1;
        if (t == 0) { float hn = s * e; y2a[0] = hn * hn; }
    }
    float v2 = (t < 64) ? cv(b2[t]) : 0.f;
    sb[t] = v2 * v2; __syncthreads();
    for (int d = 128; d > 0; d >>= 1) { if (t < d) sb[t] += sb[t + d]; __syncthreads(); }
    float n2b = sb[0]; __syncthreads();
    {
        float un = fmaxf(sqrtf(n2b), MINN);
        float e = tanhf(un), tt = e / un;
        float s = (e > MAXN) ? MAXN / e : 1.f;
        if (t < 64) hb2[t] = s * tt * v2;
        if (t == 0) { float hn = s * e; y2b[0] = hn * hn; }
    }
    for (int i = t; i < 64; i += 256) {
        blf[i] = cv(bl[i]);
        ratf[i] = cv(ratt[i]);
    }
    {
        float v = (t < 192) ? (cv(bih[t]) + cv(bhh[t])) : cv(bhh[t - 64]);
        bs256[t] = v;
    }
    for (int i = t; i < 4096; i += 256) { int k = i >> 6, n = i & 63; QT[n * 64 + k] = tb(Q[k * 64 + n]); }
    for (int i = t; i < 256 * 128; i += 256) {
        int d = i >> 7, j = i & 127;
        short v;
        if (d < 192) v = (j < 64) ? tb(Wih[d * 64 + j]) : tb(Whh[d * 64 + (j - 64)]);
        else         v = (j < 64) ? (short)0 : tb(Whh[(d - 64) * 64 + (j - 64)]);
        Wc[i] = v;
    }
}

// ---------------- CSR ----------------
__global__ void k_zero(int* __restrict__ a, int* __restrict__ b, int N) {
    int i = blockIdx.x * blockDim.x + threadIdx.x;
    if (i < N) { a[i] = 0; b[i] = 0; }
}
__global__ void k_count(const int* __restrict__ src, int E, int* __restrict__ cnt) {
    int i = blockIdx.x * blockDim.x + threadIdx.x;
    if (i < E) atomicAdd(&cnt[src[i]], 1);
}
__global__ __launch_bounds__(1024) void k_scan(const int* __restrict__ cnt, int* __restrict__ rowptr, int N) {
    __shared__ int part[1024];
    int t = threadIdx.x;
    int Cn = (N + 1023) / 1024;
    int lo = t * Cn, hi = min(lo + Cn, N);
    int s = 0;
    for (int i = lo; i < hi; ++i) s += cnt[i];
    part[t] = s; __syncthreads();
    for (int d = 1; d < 1024; d <<= 1) {
        int v = (t >= d) ? part[t - d] : 0; __syncthreads();
        part[t] += v; __syncthreads();
    }
    int run = (t == 0) ? 0 : part[t - 1];
    for (int i = lo; i < hi; ++i) { rowptr[i] = run; run += cnt[i]; }
    if (hi == N && lo < N) rowptr[N] = run;
}
__global__ void k_dis(const int* __restrict__ cnt, float* __restrict__ dis, int N) {
    int i = blockIdx.x * blockDim.x + threadIdx.x;
    if (i < N) dis[i] = 1.f / sqrtf((float)(cnt[i] + 1));
}
__global__ void k_fill(const int* __restrict__ src, const int* __restrict__ dst, int E,
                       const int* __restrict__ rowptr, int* __restrict__ fill, int* __restrict__ ecol) {
    int i = blockIdx.x * blockDim.x + threadIdx.x;
    if (i < E) {
        int s = src[i];
        int p = rowptr[s] + atomicAdd(&fill[s], 1);
        ecol[p] = dst[i];
    }
}

// --------- attention E: fused logmap0 -> (hlog@Q) -> tanh -> @r_att ------
template <typename T>
__global__ __launch_bounds__(256) void k_att_e(const T* __restrict__ hid,
                                               const short* __restrict__ QT,
                                               const float* __restrict__ ratf,
                                               float* __restrict__ Eo, int rows, const int* flag) {
    if (skip<T>(flag)) return;
    int wid = threadIdx.x >> 6, lane = threadIdx.x & 63;
    int row0 = blockIdx.x * 64 + wid * 16;
    if (row0 >= rows) return;
    int l15 = lane & 15, quad = lane >> 4;
    const T* Hrow = hid + (size_t)(row0 + l15) * 64 + quad * 8;
    float f0[8], f1[8];
    ldf8(Hrow, f0); ldf8(Hrow + 32, f1);
    float sq = 0.f;
#pragma unroll
    for (int j = 0; j < 8; ++j) sq += f0[j] * f0[j] + f1[j] * f1[j];
    sq += __shfl_xor(sq, 16); sq += __shfl_xor(sq, 32);
    float pn = fmaxf(sqrtf(sq), MINN);
    float lt = artanh_(pn) / pn;
    short8 s0, s1;
#pragma unroll
    for (int j = 0; j < 8; ++j) { s0[j] = f2b(lt * f0[j]); s1[j] = f2b(lt * f1[j]); }
    f32x4 acc[4];
#pragma unroll
    for (int nt = 0; nt < 4; ++nt) acc[nt] = (f32x4){0.f, 0.f, 0.f, 0.f};
#pragma unroll
    for (int nt = 0; nt < 4; ++nt) {
        short8 b0 = *(const short8*)(QT + (size_t)(nt * 16 + l15) * 64 + quad * 8);
        short8 b1 = *(const short8*)(QT + (size_t)(nt * 16 + l15) * 64 + 32 + quad * 8);
        acc[nt] = __builtin_amdgcn_mfma_f32_16x16x32_bf16(s0, b0, acc[nt], 0, 0, 0);
        acc[nt] = __builtin_amdgcn_mfma_f32_16x16x32_bf16(s1, b1, acc[nt], 0, 0, 0);
    }
#pragma unroll
    for (int r = 0; r < 4; ++r) {
        float s = 0.f;
#pragma unroll
        for (int nt = 0; nt < 4; ++nt) s += tanhf(acc[nt][r]) * ratf[nt * 16 + l15];
        s = red16(s);
        if (l15 == 0) Eo[row0 + quad * 4 + r] = s;
    }
}

// --------- attention combine: softmax over window, h = mean(a*hlog) -----
template <typename T>
__global__ __launch_bounds__(256) void k_att_h(const float* __restrict__ Eb, const T* __restrict__ hid,
                                               bf16* __restrict__ Hb, int N, int win, const int* flag) {
    if (skip<T>(flag)) return;
    int wid = threadIdx.x >> 6, lane = threadIdx.x & 63;
    int i = blockIdx.x * 4 + wid;
    if (i >= N) return;
    float hl[8], ev[8];
    float m = -1e30f;
    for (int w = 0; w < win; ++w) {
        float p = cv(hid[((size_t)w * N + i) * 64 + lane]);
        float pn = fmaxf(sqrtf(wave_sum(p * p)), MINN);
        hl[w] = (artanh_(pn) / pn) * p;
        ev[w] = Eb[(size_t)w * N + i];
        m = fmaxf(m, ev[w]);
    }
    float s = 0.f;
    for (int w = 0; w < win; ++w) { ev[w] = expf(ev[w] - m); s += ev[w]; }
    float h = 0.f;
    for (int w = 0; w < win; ++w) h += ev[w] * hl[w];
    ((short*)Hb)[(size_t)i * 64 + lane] = f2b(h / (s * (float)win));
}

// --------- initial linear + expmap0/proj + concat hidden + proj128 ------
template <typename T>
__global__ __launch_bounds__(256) void k_lin0(const T* __restrict__ feat, const T* __restrict__ Wl,
                                              const float* __restrict__ blf, const T* __restrict__ hid,
                                              int win, float* __restrict__ xnorm,
                                              bf16* __restrict__ outA, int N, const int* flag) {
    if (skip<T>(flag)) return;
    int wid = threadIdx.x >> 6, lane = threadIdx.x & 63;
    int row0 = blockIdx.x * 64 + wid * 16;
    if (row0 >= N) return;
    int l15 = lane & 15, quad = lane >> 4;
    f32x4 acc[4];
#pragma unroll
    for (int nt = 0; nt < 4; ++nt) acc[nt] = (f32x4){0.f, 0.f, 0.f, 0.f};
    const T* Arow = feat + (size_t)(row0 + l15) * 128 + quad * 8;
    for (int k0 = 0; k0 < 128; k0 += 32) {
        short8 a = ld8(Arow + k0);
#pragma unroll
        for (int nt = 0; nt < 4; ++nt) {
            short8 b = ld8(Wl + (size_t)(nt * 16 + l15) * 128 + k0 + quad * 8);
            acc[nt] = __builtin_amdgcn_mfma_f32_16x16x32_bf16(a, b, acc[nt], 0, 0, 0);
        }
    }
    float bv[4];
#pragma unroll
    for (int nt = 0; nt < 4; ++nt) bv[nt] = blf[nt * 16 + l15];
#pragma unroll
    for (int r = 0; r < 4; ++r) {
        int row = row0 + quad * 4 + r;
        float g[4], u2 = 0.f;
#pragma unroll
        for (int nt = 0; nt < 4; ++nt) { g[nt] = acc[nt][r] + bv[nt]; u2 += g[nt] * g[nt]; }
        u2 = red16(u2);
        float un = fmaxf(sqrtf(u2), MINN);
        float e = tanhf(un), t = e / un;
        float s1 = (e > MAXN) ? MAXN / e : 1.f;
        float x0n = s1 * e;
        float hv[4], h2 = 0.f;
#pragma unroll
        for (int nt = 0; nt < 4; ++nt) {
            hv[nt] = cv(hid[((size_t)(win - 1) * N + row) * 64 + nt * 16 + l15]);
            h2 += hv[nt] * hv[nt];
        }
        h2 = red16(h2);
        float n128 = sqrtf(x0n * x0n + h2);
        float s2 = (n128 > MAXN) ? MAXN / n128 : 1.f;
#pragma unroll
        for (int nt = 0; nt < 4; ++nt) {
            ((short*)outA)[(size_t)row * 128 + nt * 16 + l15] = f2b(s2 * s1 * t * g[nt]);
            ((short*)outA)[(size_t)row * 128 + 64 + nt * 16 + l15] = f2b(s2 * hv[nt]);
        }
        if (l15 == 0) xnorm[row] = fmaxf(fminf(n128, MAXN), MINN);
    }
}

// ------- conv linear: GEMM fused with matvec->proj->madd(hb)->proj->logmap0 ----
template <int DOUT, typename T>
__global__ __launch_bounds__(256) void k_conv_lin(const bf16* __restrict__ in, const T* __restrict__ W,
                                                  const float* __restrict__ hb, const float* __restrict__ y2p,
                                                  const float* __restrict__ xnorm,
                                                  bf16* __restrict__ out, int N, const int* flag) {
    if (skip<T>(flag)) return;
    constexpr int NT = DOUT / 16;
    int wid = threadIdx.x >> 6, lane = threadIdx.x & 63;
    int row0 = blockIdx.x * 64 + wid * 16;
    if (row0 >= N) return;
    int l15 = lane & 15, quad = lane >> 4;
    f32x4 acc[NT];
#pragma unroll
    for (int nt = 0; nt < NT; ++nt) acc[nt] = (f32x4){0.f, 0.f, 0.f, 0.f};
    const short* Arow = (const short*)in + (size_t)(row0 + l15) * 128 + quad * 8;
    for (int k0 = 0; k0 < 128; k0 += 32) {
        short8 a = *(const short8*)(Arow + k0);
#pragma unroll
        for (int nt = 0; nt < NT; ++nt) {
            short8 b = ld8(W + (size_t)(nt * 16 + l15) * 128 + k0 + quad * 8);
            acc[nt] = __builtin_amdgcn_mfma_f32_16x16x32_bf16(a, b, acc[nt], 0, 0, 0);
        }
    }
    float y2 = y2p[0];
    float hbv[NT];
#pragma unroll
    for (int nt = 0; nt < NT; ++nt) hbv[nt] = hb[nt * 16 + l15];
#pragma unroll
    for (int r = 0; r < 4; ++r) {
        int row = row0 + quad * 4 + r;
        float mx[NT], m2 = 0.f;
#pragma unroll
        for (int nt = 0; nt < NT; ++nt) { mx[nt] = acc[nt][r]; m2 += mx[nt] * mx[nt]; }
        m2 = red16(m2);
        float mxn = fmaxf(sqrtf(m2), MINN);
        float xn = xnorm[row];
        float at = artanh_(xn);
        float f = (m2 == 0.f) ? 0.f : tanhf(mxn / xn * at) / mxn;
        float rn = f * mxn;
        float s1 = (rn > MAXN) ? MAXN / rn : 1.f;
        float a_ = s1 * f, mvn = s1 * rn;
        float x2 = mvn * mvn;
        float xy = 0.f;
#pragma unroll
        for (int nt = 0; nt < NT; ++nt) xy += (a_ * mx[nt]) * hbv[nt];
        xy = red16(xy);
        float co = 1.f + 2.f * xy + y2, cx = 1.f - x2;
        float den = fmaxf(1.f + 2.f * xy + x2 * y2, MINN);
        float o[NT], on2 = 0.f;
#pragma unroll
        for (int nt = 0; nt < NT; ++nt) { o[nt] = (co * a_ * mx[nt] + cx * hbv[nt]) / den; on2 += o[nt] * o[nt]; }
        on2 = red16(on2);
        float on = sqrtf(on2);
        float s3 = (on > MAXN) ? MAXN / on : 1.f;
        float hn = fmaxf(s3 * on, MINN);
        float lt = artanh_(hn) / hn;
#pragma unroll
        for (int nt = 0; nt < NT; ++nt)
            ((short*)out)[(size_t)row * 128 + nt * 16 + l15] = f2b(lt * s3 * o[nt]);
    }
}

// --------- aggregation + expmap0/proj + HypAct [+final logmap0] ----------
template <int DPL, bool FINAL>
__global__ __launch_bounds__(256) void k_agg(const bf16* __restrict__ xt, const int* __restrict__ rowptr,
                                             const int* __restrict__ ecol, const float* __restrict__ dis,
                                             bf16* __restrict__ out, float* __restrict__ xnorm,
                                             const bf16* __restrict__ Hb, int N) {
    int wid = threadIdx.x >> 6, lane = threadIdx.x & 63;
    int i = blockIdx.x * 4 + wid;
    if (i >= N) return;
    const short* xs = (const short*)xt;
    float di = dis[i];
    float w0 = di * di;
    float a0 = w0 * b2f(xs[(size_t)i * 128 + lane]);
    float a1 = 0.f;
    if (DPL == 2) a1 = w0 * b2f(xs[(size_t)i * 128 + 64 + lane]);
    int e0 = rowptr[i], e1 = rowptr[i + 1];
    for (int j = e0; j < e1; ++j) {
        int c = ecol[j];
        float w = di * dis[c];
        a0 += w * b2f(xs[(size_t)c * 128 + lane]);
        if (DPL == 2) a1 += w * b2f(xs[(size_t)c * 128 + 64 + lane]);
    }
    float an = fmaxf(sqrtf(wave_sum(a0 * a0 + a1 * a1)), MINN);
    float e1t = tanhf(an), t1 = e1t / an;
    float s1 = (e1t > MAXN) ? MAXN / e1t : 1.f;
    float hn = fmaxf(s1 * e1t, MINN);
    float lt = artanh_(hn) / hn;
    float sht = s1 * t1 * lt;
    float v0 = sht * a0; v0 = (v0 >= 0.f) ? v0 : 0.01f * v0;
    float v1 = sht * a1; v1 = (v1 >= 0.f) ? v1 : 0.01f * v1;
    float tn = fmaxf(sqrtf(wave_sum(v0 * v0 + v1 * v1)), MINN);
    float e2 = tanhf(tn), t2 = e2 / tn;
    float s2 = (e2 > MAXN) ? MAXN / e2 : 1.f;
    float sc = s2 * t2;
    float r0 = sc * v0, r1 = sc * v1;
    if (FINAL) {
        float xnf = fmaxf(fminf(s2 * e2, MAXN), MINN);
        float lt2 = artanh_(xnf) / xnf;
        r0 *= lt2; r1 *= lt2;
    }
    short* os = (short*)out;
    os[(size_t)i * 128 + lane] = f2b(r0);
    if (DPL == 2) {
        os[(size_t)i * 128 + 64 + lane] = f2b(r1);
        if (lane == 0 && xnorm) xnorm[i] = fmaxf(fminf(e2, MAXN), MINN);
    } else {
        os[(size_t)i * 128 + 64 + lane] = ((const short*)Hb)[(size_t)i * 64 + lane];
    }
}

// --------- GRU fused + expmap0/proj -> out (templated on OUT dtype) -----
template <typename OT>
__global__ __launch_bounds__(256) void k_gru_f(const bf16* __restrict__ cat, const short* __restrict__ Wc,
                                               const float* __restrict__ bs, const bf16* __restrict__ Hb,
                                               OT* __restrict__ out, int N, const int* flag) {
    if (skip<OT>(flag)) return;
    int wid = threadIdx.x >> 6, lane = threadIdx.x & 63;
    int row0 = blockIdx.x * 64 + wid * 16;
    if (row0 >= N) return;
    int l15 = lane & 15, quad = lane >> 4;
    f32x4 acc[16];
#pragma unroll
    for (int nt = 0; nt < 16; ++nt) acc[nt] = (f32x4){0.f, 0.f, 0.f, 0.f};
    const short* Arow = (const short*)cat + (size_t)(row0 + l15) * 128 + quad * 8;
    for (int k0 = 0; k0 < 128; k0 += 32) {
        short8 a = *(const short8*)(Arow + k0);
#pragma unroll
        for (int nt = 0; nt < 16; ++nt) {
            short8 b = *(const short8*)(Wc + (size_t)(nt * 16 + l15) * 128 + k0 + quad * 8);
            acc[nt] = __builtin_amdgcn_mfma_f32_16x16x32_bf16(a, b, acc[nt], 0, 0, 0);
        }
    }
#pragma unroll
    for (int r = 0; r < 4; ++r) {
        int row = row0 + quad * 4 + r;
        float zv[4], z2 = 0.f;
#pragma unroll
        for (int nt = 0; nt < 4; ++nt) {
            int c = nt * 16 + l15;
            float gr = acc[nt][r] + bs[c];
            float gz = acc[nt + 4][r] + bs[c + 64];
            float gn = acc[nt + 8][r] + bs[c + 128];
            float hn = acc[nt + 12][r] + bs[c + 192];
            float hv = b2f(((const short*)Hb)[(size_t)row * 64 + c]);
            float rr = sigmoidf_(gr), zz = sigmoidf_(gz);
            float nn = tanhf(gn + (rr - 1.f) * hn);
            zv[nt] = (1.f - zz) * nn + zz * hv;
            z2 += zv[nt] * zv[nt];
        }
        z2 = red16(z2);
        float un = fmaxf(sqrtf(z2), MINN);
        float e = tanhf(un), t = e / un;
        float s = (e > MAXN) ? MAXN / e : 1.f;
#pragma unroll
        for (int nt = 0; nt < 4; ++nt)
            st(&out[(size_t)row * 64 + nt * 16 + l15], s * t * zv[nt]);
    }
}

extern "C" void kernel_launch(void* const* d_in, const int* in_sizes, int n_in,
                              void* d_out, int out_size, void* d_ws, size_t ws_size,
                              hipStream_t stream) {
    const int E = in_sizes[0] / 2;
    const int N = in_sizes[1] / 128;
    int win = in_sizes[14] / (N * 64); if (win > 8) win = 8;

    char* wp = (char*)d_ws;
    auto alloc = [&](size_t bytes) -> void* {
        void* p = (void*)wp;
        wp += (bytes + 255) & ~(size_t)255;
        return p;
    };
    bf16* bufA = (bf16*)alloc((size_t)N * 128 * 2);
    bf16* bufB = (bf16*)alloc((size_t)N * 128 * 2);
    bf16* Hbf  = (bf16*)alloc((size_t)N * 64 * 2);
    float* Ebuf = (float*)alloc((size_t)win * N * 4);
    float* xnorm = (float*)alloc((size_t)N * 4);
    int* cnt = (int*)alloc((size_t)N * 4);
    int* fillc = (int*)alloc((size_t)N * 4);
    int* rowptr = (int*)alloc((size_t)(N + 1) * 4);
    float* dis = (float*)alloc((size_t)N * 4);
    int* ecol = (int*)alloc((size_t)E * 4);
    float* hb1 = (float*)alloc(128 * 4);
    float* y2a = (float*)alloc(256);
    float* hb2 = (float*)alloc(64 * 4);
    float* y2b = (float*)alloc(256);
    float* blf = (float*)alloc(64 * 4);
    float* bs256 = (float*)alloc(256 * 4);
    float* ratf = (float*)alloc(64 * 4);
    short* QT = (short*)alloc(4096 * 2);
    short* Wc = (short*)alloc((size_t)256 * 128 * 2);
    int* flag = (int*)alloc(256);
    (void)ws_size; (void)out_size; (void)n_in;

    const int* ei = (const int*)d_in[0];

    k_detect<<<1, 256, 0, stream>>>(d_in[14], flag);

    // prep (both dtype variants; non-matching exits immediately)
#define P(T) (const T*)d_in
    k_prep<short><<<1, 256, 0, stream>>>(P(short)[5], P(short)[7], P(short)[3], P(short)[12], P(short)[13],
                                         P(short)[8], P(short)[9], P(short)[10], P(short)[11],
                                         hb1, y2a, hb2, y2b, blf, bs256, ratf, QT, Wc, flag);
    k_prep<float><<<1, 256, 0, stream>>>(P(float)[5], P(float)[7], P(float)[3], P(float)[12], P(float)[13],
                                         P(float)[8], P(float)[9], P(float)[10], P(float)[11],
                                         hb1, y2a, hb2, y2b, blf, bs256, ratf, QT, Wc, flag);
    // CSR build (dtype-free)
    k_zero<<<(N + 255) / 256, 256, 0, stream>>>(cnt, fillc, N);
    k_count<<<(E + 255) / 256, 256, 0, stream>>>(ei, E, cnt);
    k_scan<<<1, 1024, 0, stream>>>(cnt, rowptr, N);
    k_dis<<<(N + 255) / 256, 256, 0, stream>>>(cnt, dis, N);
    k_fill<<<(E + 255) / 256, 256, 0, stream>>>(ei, ei + E, E, rowptr, fillc, ecol);
    // HTA window attention
    int rowsHL = win * N;
    k_att_e<short><<<(rowsHL + 63) / 64, 256, 0, stream>>>(P(short)[14], QT, ratf, Ebuf, rowsHL, flag);
    k_att_e<float><<<(rowsHL + 63) / 64, 256, 0, stream>>>(P(float)[14], QT, ratf, Ebuf, rowsHL, flag);
    k_att_h<short><<<(N + 3) / 4, 256, 0, stream>>>(Ebuf, P(short)[14], Hbf, N, win, flag);
    k_att_h<float><<<(N + 3) / 4, 256, 0, stream>>>(Ebuf, P(float)[14], Hbf, N, win, flag);
    // initial linear + toHyperX + concat
    k_lin0<short><<<(N + 63) / 64, 256, 0, stream>>>(P(short)[1], P(short)[2], blf, P(short)[14], win, xnorm, bufA, N, flag);
    k_lin0<float><<<(N + 63) / 64, 256, 0, stream>>>(P(float)[1], P(float)[2], blf, P(float)[14], win, xnorm, bufA, N, flag);
    // conv1
    k_conv_lin<128, short><<<(N + 63) / 64, 256, 0, stream>>>(bufA, P(short)[4], hb1, y2a, xnorm, bufA, N, flag);
    k_conv_lin<128, float><<<(N + 63) / 64, 256, 0, stream>>>(bufA, P(float)[4], hb1, y2a, xnorm, bufA, N, flag);
    k_agg<2, false><<<(N + 3) / 4, 256, 0, stream>>>(bufA, rowptr, ecol, dis, bufB, xnorm, nullptr, N);
    // conv2
    k_conv_lin<64, short><<<(N + 63) / 64, 256, 0, stream>>>(bufB, P(short)[6], hb2, y2b, xnorm, bufB, N, flag);
    k_conv_lin<64, float><<<(N + 63) / 64, 256, 0, stream>>>(bufB, P(float)[6], hb2, y2b, xnorm, bufB, N, flag);
    k_agg<1, true><<<(N + 3) / 4, 256, 0, stream>>>(bufB, rowptr, ecol, dis, bufA, nullptr, Hbf, N);
    // GRU fused + toHyperX -> out (output dtype = detected input dtype)
    k_gru_f<short><<<(N + 63) / 64, 256, 0, stream>>>(bufA, Wc, bs256, Hbf, (short*)d_out, N, flag);
    k_gru_f<float><<<(N + 63) / 64, 256, 0, stream>>>(bufA, Wc, bs256, Hbf, (float*)d_out, N, flag);
#undef P
}